// Round 10
// baseline (801.694 us; speedup 1.0000x reference)
//
#include <hip/hip_runtime.h>
#include <math.h>

#define BQ 8
#define NT 1024
#define CIN 128
#define CO 256
#define NH 4
#define KNN 5
#define CL 256

// ---------------------------------------------------------------- init
__global__ void k_init(float* __restrict__ out, float* __restrict__ acc,
                       float* __restrict__ cnt, float* __restrict__ allw,
                       float* __restrict__ dmax) {
  int i = blockIdx.x * 256 + threadIdx.x;          // exactly BQ*NT*CO = 2097152
  acc[i] = 0.f;
  if (i < BQ * CL * CO) out[i] = 0.f;
  if (i < BQ * NT) cnt[i] = 0.f;
  if (i < BQ * CL) allw[i] = 1e-6f;
  if (i < BQ) dmax[i] = 0.f;
}

// --------------------------------------- head sum + fused row-norm (f64)
__global__ __launch_bounds__(256) void k_headsum_sqa(const float4* __restrict__ a,
                                                     float4* __restrict__ s,
                                                     double* __restrict__ sqa) {
  int blk = blockIdx.x;                            // b*1024 + row
  int t = threadIdx.x;
  int i = blk * 256 + t;                           // global float4 index
  const int per_b = NT * NT / 4;                   // 262144
  int b = i / per_b;
  int rem = i - b * per_b;
  const float4* base = a + (size_t)b * NH * per_b + rem;
  float4 v0 = base[0];
  float4 v1 = base[per_b];
  float4 v2 = base[2 * per_b];
  float4 v3 = base[3 * per_b];
  float4 o;
  o.x = (v0.x + v1.x) + (v2.x + v3.x);
  o.y = (v0.y + v1.y) + (v2.y + v3.y);
  o.z = (v0.z + v1.z) + (v2.z + v3.z);
  o.w = (v0.w + v1.w) + (v2.w + v3.w);
  s[i] = o;
  __shared__ double red[256];
  red[t] = ((double)o.x * (double)o.x + (double)o.y * (double)o.y) +
           ((double)o.z * (double)o.z + (double)o.w * (double)o.w);
  __syncthreads();
  for (int st = 128; st > 0; st >>= 1) { if (t < st) red[t] += red[t + st]; __syncthreads(); }
  if (t == 0) sqa[blk] = red[0];
}

// ---------------------------------------------------------------- 3x3 s2 conv
__global__ __launch_bounds__(256) void k_conv(const float* __restrict__ x,
                                              const float* __restrict__ w,
                                              const float* __restrict__ bias,
                                              float* __restrict__ xmapT) {
  int blk = blockIdx.x;                            // b*256 + (p*16+q)
  int b = blk >> 8;
  int pq = blk & 255;
  int p = pq >> 4, q = pq & 15;
  __shared__ __align__(16) float patch[CIN * 9];
  for (int e = threadIdx.x; e < CIN * 9; e += 256) {
    int pos = e >> 7;
    int c = e & 127;
    int dy = pos / 3, dx = pos % 3;
    int iy = 2 * p + dy - 1, ix = 2 * q + dx - 1;
    float v = 0.f;
    if (iy >= 0 && iy < 32 && ix >= 0 && ix < 32)
      v = x[((size_t)(b * NT) + iy * 32 + ix) * CIN + c];
    patch[c * 9 + pos] = v;
  }
  __syncthreads();
  int o = threadIdx.x;
  const float* wr = w + (size_t)o * CIN * 9;
  float acc = bias[o];
  for (int e = 0; e < CIN * 9; e += 4) {
    float4 w4 = *(const float4*)(wr + e);
    float4 p4 = *(const float4*)(patch + e);
    acc = fmaf(w4.x, p4.x, acc);
    acc = fmaf(w4.y, p4.y, acc);
    acc = fmaf(w4.z, p4.z, acc);
    acc = fmaf(w4.w, p4.w, acc);
  }
  xmapT[(((size_t)(b << 8) | pq) << 8) + o] = acc;
}

// ---------------------------------------------------------------- map2token
__global__ void k_m2t(const float* __restrict__ xmapT, const int* __restrict__ idx_token,
                      float* __restrict__ acc, float* __restrict__ cnt) {
  int blk = blockIdx.x;
  int b = blk >> 10;
  int cell = blk & 1023;
  int i = cell >> 5, j = cell & 31;
  int cell16 = (i >> 1) * 16 + (j >> 1);
  int t = idx_token[b * NT + cell];
  int o = threadIdx.x;
  float v = xmapT[(((size_t)(b << 8) | cell16) << 8) + o];
  atomicAdd(&acc[((size_t)(b * NT + t) << 8) + o], v);
  if (o == 0) atomicAdd(&cnt[b * NT + t], 1.0f);
}

// ------------------- skip GEMM + LN + score + fused row-norm (f64)
__global__ __launch_bounds__(256) void k_token(const float* __restrict__ x,
                                               const float* __restrict__ skw,
                                               const float* __restrict__ acc,
                                               const float* __restrict__ cnt,
                                               const float* __restrict__ lng,
                                               const float* __restrict__ lnb,
                                               const float* __restrict__ scw,
                                               const float* __restrict__ scb,
                                               float* __restrict__ xn,
                                               double* __restrict__ sqx,
                                               float* __restrict__ tw) {
  int blk = blockIdx.x;
  int b = blk >> 10, n = blk & 1023;
  __shared__ __align__(16) float xrow[CIN];
  __shared__ float red[256];
  __shared__ double redd[256];
  int o = threadIdx.x;
  if (o < CIN) xrow[o] = x[(size_t)(b * NT + n) * CIN + o];
  __syncthreads();
  const float* sw = skw + (size_t)o * CIN;
  float s = 0.f;
  for (int c = 0; c < CIN; c += 4) {
    float4 w4 = *(const float4*)(sw + c);
    float4 x4 = *(const float4*)(xrow + c);
    s = fmaf(w4.x, x4.x, s);
    s = fmaf(w4.y, x4.y, s);
    s = fmaf(w4.z, x4.z, s);
    s = fmaf(w4.w, x4.w, s);
  }
  float cdiv = cnt[b * NT + n] + 1e-6f;
  float val = s + acc[((size_t)(b * NT + n) << 8) + o] / cdiv;

  red[o] = val;
  __syncthreads();
  for (int st = 128; st > 0; st >>= 1) { if (o < st) red[o] += red[o + st]; __syncthreads(); }
  float mu = red[0] * (1.0f / 256.0f);
  __syncthreads();
  float d = val - mu;
  red[o] = d * d;
  __syncthreads();
  for (int st = 128; st > 0; st >>= 1) { if (o < st) red[o] += red[o + st]; __syncthreads(); }
  float var = red[0] * (1.0f / 256.0f);
  __syncthreads();
  float xv = d / sqrtf(var + 1e-5f) * lng[o] + lnb[o];
  xn[((size_t)(b * NT + n) << 8) + o] = xv;
  redd[o] = (double)xv * (double)xv;
  __syncthreads();
  for (int st = 128; st > 0; st >>= 1) { if (o < st) redd[o] += redd[o + st]; __syncthreads(); }
  if (o == 0) sqx[b * NT + n] = redd[0];
  __syncthreads();
  red[o] = xv * scw[o];
  __syncthreads();
  for (int st = 128; st > 0; st >>= 1) { if (o < st) red[o] += red[o + st]; __syncthreads(); }
  if (o == 0) tw[b * NT + n] = expf(red[0] + scb[0]);
}

// ------------------- fused dual-Gram dist, TRIANGULAR grid + mirror write
__global__ __launch_bounds__(256) void k_dist_tri(const float* __restrict__ xn,
                                                  const float* __restrict__ asum,
                                                  const double* __restrict__ sqx,
                                                  const double* __restrict__ sqa,
                                                  float* __restrict__ dist,
                                                  float* __restrict__ dmax) {
  const int b = blockIdx.y;
  int rem = blockIdx.x;
  int ti = 0;
  while (rem >= 16 - ti) { rem -= 16 - ti; ++ti; }
  const int tj = ti + rem;
  const int i0 = ti << 6;
  const int j0 = tj << 6;
  const int t = threadIdx.x;
  const int tx = t & 15;
  const int ty = t >> 4;
  const int rr = t >> 3;
  const int gg = t & 7;

  __shared__ __align__(16) float SM[4352];
  float* At = SM;
  float* Bt = SM + 2176;

  double dxa[4][4], daa[4][4];
#pragma unroll
  for (int r = 0; r < 4; ++r)
#pragma unroll
    for (int c = 0; c < 4; ++c) { dxa[r][c] = 0.0; daa[r][c] = 0.0; }

  const float* xb = xn + (size_t)b * NT * CO;
  float4 pa0 = *(const float4*)(xb + (size_t)(i0 + rr) * CO + 4 * gg);
  float4 pa1 = *(const float4*)(xb + (size_t)(i0 + rr + 32) * CO + 4 * gg);
  float4 pb0 = *(const float4*)(xb + (size_t)(j0 + rr) * CO + 4 * gg);
  float4 pb1 = *(const float4*)(xb + (size_t)(j0 + rr + 32) * CO + 4 * gg);
  for (int kc = 0; kc < CO; kc += 32) {
    At[(4 * gg + 0) * 68 + rr] = pa0.x;
    At[(4 * gg + 1) * 68 + rr] = pa0.y;
    At[(4 * gg + 2) * 68 + rr] = pa0.z;
    At[(4 * gg + 3) * 68 + rr] = pa0.w;
    At[(4 * gg + 0) * 68 + rr + 32] = pa1.x;
    At[(4 * gg + 1) * 68 + rr + 32] = pa1.y;
    At[(4 * gg + 2) * 68 + rr + 32] = pa1.z;
    At[(4 * gg + 3) * 68 + rr + 32] = pa1.w;
    Bt[(4 * gg + 0) * 68 + rr] = pb0.x;
    Bt[(4 * gg + 1) * 68 + rr] = pb0.y;
    Bt[(4 * gg + 2) * 68 + rr] = pb0.z;
    Bt[(4 * gg + 3) * 68 + rr] = pb0.w;
    Bt[(4 * gg + 0) * 68 + rr + 32] = pb1.x;
    Bt[(4 * gg + 1) * 68 + rr + 32] = pb1.y;
    Bt[(4 * gg + 2) * 68 + rr + 32] = pb1.z;
    Bt[(4 * gg + 3) * 68 + rr + 32] = pb1.w;
    __syncthreads();
    int kn = (kc + 32 < CO) ? kc + 32 : 0;
    pa0 = *(const float4*)(xb + (size_t)(i0 + rr) * CO + kn + 4 * gg);
    pa1 = *(const float4*)(xb + (size_t)(i0 + rr + 32) * CO + kn + 4 * gg);
    pb0 = *(const float4*)(xb + (size_t)(j0 + rr) * CO + kn + 4 * gg);
    pb1 = *(const float4*)(xb + (size_t)(j0 + rr + 32) * CO + kn + 4 * gg);
    float f[4][4] = {};
#pragma unroll 8
    for (int kk = 0; kk < 32; ++kk) {
      float4 a4 = *(const float4*)(&At[kk * 68 + (ty << 2)]);
      float4 b4 = *(const float4*)(&Bt[kk * 68 + (tx << 2)]);
      float av[4] = {a4.x, a4.y, a4.z, a4.w};
      float bv[4] = {b4.x, b4.y, b4.z, b4.w};
#pragma unroll
      for (int r = 0; r < 4; ++r)
#pragma unroll
        for (int c = 0; c < 4; ++c) f[r][c] = fmaf(av[r], bv[c], f[r][c]);
    }
#pragma unroll
    for (int r = 0; r < 4; ++r)
#pragma unroll
      for (int c = 0; c < 4; ++c) dxa[r][c] += (double)f[r][c];
    __syncthreads();
  }

  const float* ab = asum + (size_t)b * NT * NT;
  pa0 = *(const float4*)(ab + (size_t)(i0 + rr) * NT + 4 * gg);
  pa1 = *(const float4*)(ab + (size_t)(i0 + rr + 32) * NT + 4 * gg);
  pb0 = *(const float4*)(ab + (size_t)(j0 + rr) * NT + 4 * gg);
  pb1 = *(const float4*)(ab + (size_t)(j0 + rr + 32) * NT + 4 * gg);
  for (int kc = 0; kc < NT; kc += 32) {
    At[(4 * gg + 0) * 68 + rr] = pa0.x;
    At[(4 * gg + 1) * 68 + rr] = pa0.y;
    At[(4 * gg + 2) * 68 + rr] = pa0.z;
    At[(4 * gg + 3) * 68 + rr] = pa0.w;
    At[(4 * gg + 0) * 68 + rr + 32] = pa1.x;
    At[(4 * gg + 1) * 68 + rr + 32] = pa1.y;
    At[(4 * gg + 2) * 68 + rr + 32] = pa1.z;
    At[(4 * gg + 3) * 68 + rr + 32] = pa1.w;
    Bt[(4 * gg + 0) * 68 + rr] = pb0.x;
    Bt[(4 * gg + 1) * 68 + rr] = pb0.y;
    Bt[(4 * gg + 2) * 68 + rr] = pb0.z;
    Bt[(4 * gg + 3) * 68 + rr] = pb0.w;
    Bt[(4 * gg + 0) * 68 + rr + 32] = pb1.x;
    Bt[(4 * gg + 1) * 68 + rr + 32] = pb1.y;
    Bt[(4 * gg + 2) * 68 + rr + 32] = pb1.z;
    Bt[(4 * gg + 3) * 68 + rr + 32] = pb1.w;
    __syncthreads();
    int kn = (kc + 32 < NT) ? kc + 32 : 0;
    pa0 = *(const float4*)(ab + (size_t)(i0 + rr) * NT + kn + 4 * gg);
    pa1 = *(const float4*)(ab + (size_t)(i0 + rr + 32) * NT + kn + 4 * gg);
    pb0 = *(const float4*)(ab + (size_t)(j0 + rr) * NT + kn + 4 * gg);
    pb1 = *(const float4*)(ab + (size_t)(j0 + rr + 32) * NT + kn + 4 * gg);
    float f[4][4] = {};
#pragma unroll 8
    for (int kk = 0; kk < 32; ++kk) {
      float4 a4 = *(const float4*)(&At[kk * 68 + (ty << 2)]);
      float4 b4 = *(const float4*)(&Bt[kk * 68 + (tx << 2)]);
      float av[4] = {a4.x, a4.y, a4.z, a4.w};
      float bv[4] = {b4.x, b4.y, b4.z, b4.w};
#pragma unroll
      for (int r = 0; r < 4; ++r)
#pragma unroll
        for (int c = 0; c < 4; ++c) f[r][c] = fmaf(av[r], bv[c], f[r][c]);
    }
#pragma unroll
    for (int r = 0; r < 4; ++r)
#pragma unroll
      for (int c = 0; c < 4; ++c) daa[r][c] += (double)f[r][c];
    __syncthreads();
  }

  double sxi[4], sai[4], sxj[4], saj[4];
#pragma unroll
  for (int r = 0; r < 4; ++r) {
    sxi[r] = sqx[(size_t)b * NT + i0 + (ty << 2) + r];
    sai[r] = sqa[(size_t)b * NT + i0 + (ty << 2) + r];
  }
#pragma unroll
  for (int c = 0; c < 4; ++c) {
    sxj[c] = sqx[(size_t)b * NT + j0 + (tx << 2) + c];
    saj[c] = sqa[(size_t)b * NT + j0 + (tx << 2) + c];
  }
  const double sc = 0.0625;
  float ov[4][4];
  float mx = 0.f;
#pragma unroll
  for (int r = 0; r < 4; ++r) {
#pragma unroll
    for (int c = 0; c < 4; ++c) {
      double d2x = sxi[r] + sxj[c] - 2.0 * dxa[r][c];
      double d2a = sai[r] + saj[c] - 2.0 * daa[r][c];
      float v = (float)(0.8 * (sqrt(fmax(d2x, 0.0)) * sc) +
                        0.2 * (sqrt(fmax(d2a, 0.0)) * sc));
      ov[r][c] = v;
      mx = fmaxf(mx, v);
    }
    float4 o4 = {ov[r][0], ov[r][1], ov[r][2], ov[r][3]};
    *(float4*)&dist[((size_t)b * NT + i0 + (ty << 2) + r) * NT + j0 + (tx << 2)] = o4;
  }

  if (ti != tj) {
    float* tile = SM;
#pragma unroll
    for (int r = 0; r < 4; ++r)
#pragma unroll
      for (int c = 0; c < 4; ++c)
        tile[((ty << 2) + r) * 65 + (tx << 2) + c] = ov[r][c];
    __syncthreads();
#pragma unroll
    for (int r = 0; r < 4; ++r) {
      float4 o4;
      o4.x = tile[((tx << 2) + 0) * 65 + (ty << 2) + r];
      o4.y = tile[((tx << 2) + 1) * 65 + (ty << 2) + r];
      o4.z = tile[((tx << 2) + 2) * 65 + (ty << 2) + r];
      o4.w = tile[((tx << 2) + 3) * 65 + (ty << 2) + r];
      *(float4*)&dist[((size_t)b * NT + j0 + (ty << 2) + r) * NT + i0 + (tx << 2)] = o4;
    }
  }

  for (int off = 32; off > 0; off >>= 1) mx = fmaxf(mx, __shfl_xor(mx, off));
  if ((t & 63) == 0) atomicMax((int*)&dmax[b], __float_as_int(mx));
}

// ---------------------------------------------------------------- threefry (jax)
__device__ __forceinline__ unsigned rotl32(unsigned x, int d) {
  return (x << d) | (x >> (32 - d));
}
__device__ void threefry2x32(unsigned k0, unsigned k1, unsigned c0, unsigned c1,
                             unsigned* o0, unsigned* o1) {
  unsigned ks2 = k0 ^ k1 ^ 0x1BD11BDAu;
  unsigned x0 = c0 + k0, x1 = c1 + k1;
  const int r0[4] = {13, 15, 26, 6}, r1[4] = {17, 29, 16, 24};
#pragma unroll
  for (int i = 0; i < 4; ++i) { x0 += x1; x1 = rotl32(x1, r0[i]); x1 ^= x0; }
  x0 += k1; x1 += ks2 + 1u;
#pragma unroll
  for (int i = 0; i < 4; ++i) { x0 += x1; x1 = rotl32(x1, r1[i]); x1 ^= x0; }
  x0 += ks2; x1 += k0 + 2u;
#pragma unroll
  for (int i = 0; i < 4; ++i) { x0 += x1; x1 = rotl32(x1, r0[i]); x1 ^= x0; }
  x0 += k0; x1 += k1 + 3u;
#pragma unroll
  for (int i = 0; i < 4; ++i) { x0 += x1; x1 = rotl32(x1, r1[i]); x1 ^= x0; }
  x0 += k1; x1 += ks2 + 4u;
#pragma unroll
  for (int i = 0; i < 4; ++i) { x0 += x1; x1 = rotl32(x1, r0[i]); x1 ^= x0; }
  x0 += ks2; x1 += k0 + 5u;
  *o0 = x0; *o1 = x1;
}

// ---------------------------------------------------------------- 5-NN density
__global__ __launch_bounds__(256) void k_knn(const float* __restrict__ dist,
                                             float* __restrict__ density) {
  int row = blockIdx.x;                            // b*NT + i
  int t = threadIdx.x;
  __shared__ float drow[NT];
  __shared__ float wv[4];
  __shared__ int wi[4];
  float4 v4 = *(const float4*)(dist + (size_t)row * NT + 4 * t);
  drow[4 * t] = v4.x; drow[4 * t + 1] = v4.y;
  drow[4 * t + 2] = v4.z; drow[4 * t + 3] = v4.w;
  __syncthreads();
  float ssum = 0.f;
  for (int r = 0; r < KNN; ++r) {
    float bv = 1e30f;
    int bi = NT;
    for (int k = t; k < NT; k += 256) {
      float v = drow[k];
      if (v < bv || (v == bv && k < bi)) { bv = v; bi = k; }
    }
    for (int off = 32; off > 0; off >>= 1) {
      float ov = __shfl_xor(bv, off);
      int oi = __shfl_xor(bi, off);
      if (ov < bv || (ov == bv && oi < bi)) { bv = ov; bi = oi; }
    }
    if ((t & 63) == 0) { wv[t >> 6] = bv; wi[t >> 6] = bi; }
    __syncthreads();
    bv = wv[0]; bi = wi[0];
#pragma unroll
    for (int w2 = 1; w2 < 4; ++w2) {
      float ov = wv[w2];
      int oi = wi[w2];
      if (ov < bv || (ov == bv && oi < bi)) { bv = ov; bi = oi; }
    }
    ssum += bv * bv;
    if (t == 0) drow[bi] = 1e30f;
    __syncthreads();
  }
  if (t == 0) {
    unsigned i = (unsigned)row;
    unsigned c0 = (i < 4096u) ? i : i - 4096u;
    unsigned c1 = c0 + 4096u;
    unsigned o0, o1;
    threefry2x32(0u, 42u, c0, c1, &o0, &o1);
    unsigned bits = (i < 4096u) ? o0 : o1;
    float u = __uint_as_float((bits >> 9) | 0x3f800000u) - 1.0f;
    density[row] = expf(-(ssum * (1.0f / 5.0f))) + u * 1e-6f;
  }
}

// ---------------------------------------------------------------- dmin + score
__global__ __launch_bounds__(256) void k_dmin(const float* __restrict__ dist,
                                              const float* __restrict__ density,
                                              const float* __restrict__ as_out,
                                              const float* __restrict__ dmax,
                                              float* __restrict__ score) {
  int row = blockIdx.x;
  int b = row >> 10;
  int i = row & 1023;
  const float* dr = dist + (size_t)row * NT;
  const float* den = density + b * NT;
  float di = den[i];
  float dm = dmax[b];
  __shared__ float red[256];
  float m = dm;
  for (int k = threadIdx.x; k < NT; k += 256) {
    float v = (den[k] > di) ? dr[k] : dm;
    m = fminf(m, v);
  }
  red[threadIdx.x] = m;
  __syncthreads();
  for (int st = 128; st > 0; st >>= 1) {
    if (threadIdx.x < st) red[threadIdx.x] = fminf(red[threadIdx.x], red[threadIdx.x + st]);
    __syncthreads();
  }
  if (threadIdx.x == 0) score[row] = red[0] * di + as_out[row];
}

// ---------------------------------------------------------------- top-256 (bitonic)
__global__ __launch_bounds__(1024) void k_topk(const float* __restrict__ score,
                                               int* __restrict__ idx_down) {
  int b = blockIdx.x, t = threadIdx.x;
  __shared__ unsigned long long keys[1024];
  float v = score[b * NT + t];
  unsigned u = __float_as_uint(v);
  u = (u & 0x80000000u) ? ~u : (u | 0x80000000u);
  unsigned inv = ~u;
  keys[t] = ((unsigned long long)inv << 32) | (unsigned)t;
  __syncthreads();
  for (int k = 2; k <= 1024; k <<= 1) {
    for (int j = k >> 1; j > 0; j >>= 1) {
      int ixj = t ^ j;
      if (ixj > t) {
        bool up = ((t & k) == 0);
        unsigned long long a = keys[t], c = keys[ixj];
        if ((a > c) == up) { keys[t] = c; keys[ixj] = a; }
      }
      __syncthreads();
    }
  }
  if (t < CL) idx_down[b * CL + t] = (int)(keys[t] & 0xFFFFFFFFu);
}

// ---------------------------------------------------------------- argmin assign
__global__ __launch_bounds__(256) void k_assign(const float* __restrict__ dist,
                                                const int* __restrict__ idx_down,
                                                int* __restrict__ idxc) {
  int b = blockIdx.y;
  int n = blockIdx.x * 256 + threadIdx.x;
  __shared__ int cs[CL];
  cs[threadIdx.x] = idx_down[b * CL + threadIdx.x];
  __syncthreads();
  const float* db = dist + (size_t)b * NT * NT;
  float bv = 1e30f;
  int bj = 0;
  for (int j = 0; j < CL; ++j) {
    float v = db[(size_t)cs[j] * NT + n];
    if (v < bv) { bv = v; bj = j; }
  }
  idxc[b * NT + n] = bj;
}

__global__ void k_over(const int* __restrict__ idx_down, int* __restrict__ idxc) {
  int b = blockIdx.x, j = threadIdx.x;
  idxc[b * NT + idx_down[b * CL + j]] = j;
}

// ---------------------------------------------------------------- merge
__global__ void k_allw(const int* __restrict__ idxc, const float* __restrict__ tw,
                       float* __restrict__ allw) {
  int r = blockIdx.x * 256 + threadIdx.x;          // B*NT
  int b = r >> 10;
  atomicAdd(&allw[b * CL + idxc[r]], tw[r]);
}

__global__ __launch_bounds__(256) void k_merge(const float* __restrict__ xn,
                                               const int* __restrict__ idxc,
                                               const float* __restrict__ tw,
                                               const float* __restrict__ allw,
                                               float* __restrict__ out) {
  int r = blockIdx.x;                              // b*NT + n
  int b = r >> 10;
  int k = idxc[r];
  float w = tw[r] / allw[b * CL + k];
  int o = threadIdx.x;
  atomicAdd(&out[((size_t)(b * CL + k) << 8) + o], xn[((size_t)r << 8) + o] * w);
}

// ---------------------------------------------------------------- launch
extern "C" void kernel_launch(void* const* d_in, const int* in_sizes, int n_in,
                              void* d_out, int out_size, void* d_ws, size_t ws_size,
                              hipStream_t stream) {
  (void)in_sizes; (void)n_in; (void)out_size; (void)ws_size;
  const float* x       = (const float*)d_in[0];
  const float* attn    = (const float*)d_in[1];
  const float* as_out  = (const float*)d_in[2];
  const float* conv_w  = (const float*)d_in[3];
  const float* conv_b  = (const float*)d_in[4];
  const float* skip_w  = (const float*)d_in[5];
  const float* ln_g    = (const float*)d_in[6];
  const float* ln_b    = (const float*)d_in[7];
  const float* score_w = (const float*)d_in[8];
  const float* score_b = (const float*)d_in[9];
  const int*   idx_tok = (const int*)d_in[10];
  float* out = (float*)d_out;

  char* p = (char*)d_ws;                           // round-1 layout verbatim (~86.3 MB)
  float*  asum    = (float*)(p);                   // 33554432 B
  float*  dist    = (float*)(p + 33554432);        // 33554432 B
  float*  xmapT   = (float*)(p + 67108864);        //  2097152 B
  float*  acc     = (float*)(p + 69206016);        //  8388608 B
  float*  cnt     = (float*)(p + 77594624);        //    32768 B
  float*  xn      = (float*)(p + 77627392);        //  8388608 B
  float*  tw      = (float*)(p + 86016000);        //    32768 B
  double* sqx     = (double*)(p + 86048768);       //    65536 B
  double* sqa     = (double*)(p + 86114304);       //    65536 B
  float*  density = (float*)(p + 86179840);        //    32768 B
  float*  score   = (float*)(p + 86212608);        //    32768 B
  float*  dmax    = (float*)(p + 86245376);        //      256 B
  int*    idxdown = (int*)(p + 86245632);          //     8192 B
  int*    idxc    = (int*)(p + 86253824);          //    32768 B
  float*  allw    = (float*)(p + 86286592);        //     8192 B

  k_init<<<8192, 256, 0, stream>>>(out, acc, cnt, allw, dmax);
  k_headsum_sqa<<<8192, 256, 0, stream>>>((const float4*)attn, (float4*)asum, sqa);
  k_conv<<<2048, 256, 0, stream>>>(x, conv_w, conv_b, xmapT);
  k_m2t<<<8192, 256, 0, stream>>>(xmapT, idx_tok, acc, cnt);
  k_token<<<8192, 256, 0, stream>>>(x, skip_w, acc, cnt, ln_g, ln_b, score_w, score_b,
                                    xn, sqx, tw);
  k_dist_tri<<<dim3(136, 8), 256, 0, stream>>>(xn, asum, sqx, sqa, dist, dmax);
  k_knn<<<8192, 256, 0, stream>>>(dist, density);
  k_dmin<<<8192, 256, 0, stream>>>(dist, density, as_out, dmax, score);
  k_topk<<<8, 1024, 0, stream>>>(score, idxdown);
  k_assign<<<dim3(4, 8), 256, 0, stream>>>(dist, idxdown, idxc);
  k_over<<<8, 256, 0, stream>>>(idxdown, idxc);
  k_allw<<<32, 256, 0, stream>>>(idxc, tw, allw);
  k_merge<<<8192, 256, 0, stream>>>(xn, idxc, tw, allw, out);
}